// Round 15
// baseline (214.104 us; speedup 1.0000x reference)
//
#include <hip/hip_runtime.h>

#define B_  2
#define S_  512
#define E2_ 512
#define E_  256

#define TT  128   // t-tile (fragment-major A layout granularity)
#define KB  32    // k-tile per step

using f32x4 = __attribute__((ext_vector_type(4))) float;
using f16x8 = __attribute__((ext_vector_type(8))) _Float16;

__device__ __forceinline__ float tanh_fast(float x) {
    // NaN-safe: e->inf gives 1-0=1 ; e->0 gives 1-2=-1
    float e = __expf(2.0f * x);
    return 1.0f - 2.0f / (e + 1.0f);
}

// ---- prep A: q f32 [b][t][k] -> qhp f16 [b][ti][ko][row][kk]  (1 MB) -----------
// 512 blocks x 256 threads x 4 elems = 524288 exact.
__global__ void prep_qhp(const float* __restrict__ q, _Float16* __restrict__ qhp) {
    int idx = blockIdx.x * 256 + threadIdx.x;   // 0 .. 131071
    int e   = idx * 4;
    int b   = e >> 18;
    int rem = e & 262143;
    int t   = rem >> 9;
    int k   = rem & 511;
    int ti = t >> 7, row = t & 127;
    int ko = k >> 5, kk  = k & 31;
    float4 v = *(const float4*)(q + e);
    _Float16 h4[4] = {(_Float16)v.x, (_Float16)v.y, (_Float16)v.z, (_Float16)v.w};
    _Float16* dst = qhp + ((((size_t)(b * 4 + ti) * 16 + ko) * 128 + row) * 32 + kk);
    *(short4*)dst = *(short4*)h4;
}

// ---- prep B: Wd f32 [k][d] -> wp2 f16 [ko][d][kk]  (256 KB) --------------------
__global__ void prep_w(const float* __restrict__ Wd, _Float16* __restrict__ Wp2) {
    int idx = blockIdx.x * 256 + threadIdx.x;   // 0 .. 131071
    int h = idx >> 8;      // k index 0..511
    int d = idx & 255;     // 0..255
    int ko = h >> 5;
    int kk = h & 31;
    Wp2[ko * (E_ * KB) + d * KB + kk] = (_Float16)Wd[idx];
}

// ---------------- stage1: logits[b,s,t], triangular grid, barrier-free k-loop ----
// blockIdx.x in [0,1280): p = x>>7 tile-pair (ti<=sj), sl = x&127 selects s
__global__ __launch_bounds__(512, 4)
void stage1(const _Float16* __restrict__ qhp,
            const _Float16* __restrict__ Wp2,
            const _Float16* __restrict__ qh_rows,  /* qhp again; s-row gather below */
            const float* __restrict__ vd,
            float* __restrict__ logits /* [B*S, S] */) {
    const int p  = blockIdx.x >> 7;
    const int sl = blockIdx.x & 127;
    const int b  = blockIdx.y;
    const int sj = (p >= 6) ? 3 : (p >= 3) ? 2 : (p >= 1) ? 1 : 0;
    const int ti = p - ((sj * (sj + 1)) >> 1);
    const int s  = sj * TT + sl;
    const int t0 = ti * TT;

    __shared__ _Float16 sQsh[E2_];   // qh_s row, fragment-major per ko slice
    __shared__ float    sVd[E_];
    __shared__ float    sRed[TT * 4];

    const int tid = threadIdx.x;   // 0..511
    {
        // gather s-row from qhp layout: k = tid -> (ko, kk); row = s&127, tile = sj
        int ko = tid >> 5, kk = tid & 31;
        sQsh[tid] = qhp[(((size_t)(b * 4 + sj) * 16 + ko) * 128 + (s & 127)) * 32 + kk];
        if (tid < E_) sVd[tid] = vd[tid];
    }
    __syncthreads();

    const int wave = tid >> 6;    // 0..7
    const int lane = tid & 63;
    const int wt   = wave >> 2;   // 0..1 : t-half (64 rows)
    const int wd   = wave & 3;    // 0..3 : d-quarter (64 cols)
    const int l15  = lane & 15;
    const int l4   = lane >> 4;   // 0..3

    // fragment-major, fully coalesced base pointers (each wave load = 1KB contiguous)
    const _Float16* qa = qhp + ((size_t)(b * 4 + ti) * 16) * 4096 + (wt * 64 + l15) * 32 + l4 * 8;
    const _Float16* wb = Wp2 + (wd * 64 + l15) * KB + l4 * 8;

    f32x4 acc[4][4] = {};

#pragma unroll
    for (int ko = 0; ko < 16; ++ko) {
        f16x8 af[4], bf[4], pa[4];
        const _Float16* qk = qa + ko * 4096;
        const _Float16* wk = wb + ko * (E_ * KB);
#pragma unroll
        for (int ft = 0; ft < 4; ++ft)
            af[ft] = *(const f16x8*)(qk + ft * 16 * 32);
#pragma unroll
        for (int fd = 0; fd < 4; ++fd)
            bf[fd] = *(const f16x8*)(wk + fd * 16 * KB);
        f16x8 qsv = *(const f16x8*)&sQsh[ko * KB + l4 * 8];
#pragma unroll
        for (int ft = 0; ft < 4; ++ft)
            pa[ft] = af[ft] * qsv;          // v_pk_mul_f16 x4
#pragma unroll
        for (int ft = 0; ft < 4; ++ft)
#pragma unroll
            for (int fd = 0; fd < 4; ++fd)
                acc[ft][fd] = __builtin_amdgcn_mfma_f32_16x16x32_f16(pa[ft], bf[fd], acc[ft][fd], 0, 0, 0);
    }

    // ---- epilogue: tanh, *vd, reduce over d
    {
        float vdr[4];
#pragma unroll
        for (int fd = 0; fd < 4; ++fd) vdr[fd] = sVd[wd * 64 + fd * 16 + l15];
#pragma unroll
        for (int ft = 0; ft < 4; ++ft) {
#pragma unroll
            for (int r = 0; r < 4; ++r) {
                float pp = 0.f;
#pragma unroll
                for (int fd = 0; fd < 4; ++fd)
                    pp += tanh_fast(acc[ft][fd][r]) * vdr[fd];
                pp += __shfl_xor(pp, 1);
                pp += __shfl_xor(pp, 2);
                pp += __shfl_xor(pp, 4);
                pp += __shfl_xor(pp, 8);
                if (l15 == 0) {
                    int tl = wt * 64 + ft * 16 + l4 * 4 + r;
                    sRed[tl * 4 + wd] = pp;
                }
            }
        }
    }
    __syncthreads();
    if (tid < TT) {
        float v = sRed[tid * 4 + 0] + sRed[tid * 4 + 1] + sRed[tid * 4 + 2] + sRed[tid * 4 + 3];
        int t = t0 + tid;
        logits[((size_t)(b * S_ + s)) * S_ + t] = v;   // direct
        logits[((size_t)(b * S_ + t)) * S_ + s] = v;   // mirror (bitwise-identical)
    }
}

// ---------------- softmax in place over rows of 512 ------------------------------
__global__ void softmax_k(float* __restrict__ atten) {
    const int row  = blockIdx.x;
    const int lane = threadIdx.x;
    float* p = atten + (size_t)row * S_;
    float4 v0 = *(float4*)(p + lane * 8);
    float4 v1 = *(float4*)(p + lane * 8 + 4);
    float vv[8] = {v0.x, v0.y, v0.z, v0.w, v1.x, v1.y, v1.z, v1.w};
    float m = vv[0];
#pragma unroll
    for (int j = 1; j < 8; ++j) m = fmaxf(m, vv[j]);
#pragma unroll
    for (int off = 1; off < 64; off <<= 1) m = fmaxf(m, __shfl_xor(m, off));
    float ssum = 0.f;
#pragma unroll
    for (int j = 0; j < 8; ++j) { vv[j] = __expf(vv[j] - m); ssum += vv[j]; }
#pragma unroll
    for (int off = 1; off < 64; off <<= 1) ssum += __shfl_xor(ssum, off);
    float inv = 1.0f / ssum;
    float4 o0 = {vv[0] * inv, vv[1] * inv, vv[2] * inv, vv[3] * inv};
    float4 o1 = {vv[4] * inv, vv[5] * inv, vv[6] * inv, vv[7] * inv};
    *(float4*)(p + lane * 8)     = o0;
    *(float4*)(p + lane * 8 + 4) = o1;
}

// ---------------- context = atten @ value (f32 tiled) -----------------------------
__global__ __launch_bounds__(256)
void context_k(const float* __restrict__ atten, const float* __restrict__ value,
               float* __restrict__ ctx) {
    __shared__ float sA[32][65];
    __shared__ float sV[64][65];
    const int b  = blockIdx.z;
    const int s0 = blockIdx.y * 32;
    const int e0 = blockIdx.x * 64;
    const int tid = threadIdx.x;
    const int ts = tid >> 4;
    const int te = tid & 15;

    float acc[2][4] = {};
    for (int k0 = 0; k0 < S_; k0 += 64) {
        {
            int r = tid >> 3;
            int c = (tid & 7) * 8;
            const float* ga = atten + ((size_t)(b * S_ + s0 + r)) * S_ + k0 + c;
            *(float4*)&sA[r][c]     = *(const float4*)ga;
            *(float4*)&sA[r][c + 4] = *(const float4*)(ga + 4);
        }
        {
            int r = tid >> 2;
            int c = (tid & 3) * 16;
            const float* gv = value + ((size_t)(b * S_ + k0 + r)) * E2_ + e0 + c;
#pragma unroll
            for (int j = 0; j < 16; j += 4)
                *(float4*)&sV[r][c + j] = *(const float4*)(gv + j);
        }
        __syncthreads();
#pragma unroll 8
        for (int kk = 0; kk < 64; ++kk) {
            float a0 = sA[ts * 2 + 0][kk];
            float a1 = sA[ts * 2 + 1][kk];
#pragma unroll
            for (int j = 0; j < 4; ++j) {
                float vvv = sV[kk][te * 4 + j];
                acc[0][j] += a0 * vvv;
                acc[1][j] += a1 * vvv;
            }
        }
        __syncthreads();
    }
#pragma unroll
    for (int i = 0; i < 2; ++i)
#pragma unroll
        for (int j = 0; j < 4; ++j)
            ctx[((size_t)(b * S_ + s0 + ts * 2 + i)) * E2_ + e0 + te * 4 + j] = acc[i][j];
}

extern "C" void kernel_launch(void* const* d_in, const int* in_sizes, int n_in,
                              void* d_out, int out_size, void* d_ws, size_t ws_size,
                              hipStream_t stream) {
    const float* query = (const float*)d_in[0];
    const float* value = (const float*)d_in[1];
    const float* Wd    = (const float*)d_in[2];
    const float* vd    = (const float*)d_in[3];

    float* out   = (float*)d_out;
    float* ctx   = out;                          // [B,S,E2]  (2 MB)
    float* atten = out + (size_t)B_ * S_ * E2_;  // [B,S,S]

    // scratch: qhp (1 MB) + wp2 (256 KB)
    const size_t need = (size_t)(B_ * S_ * E2_ + 16 * E_ * KB) * sizeof(_Float16);
    _Float16* qhp;
    if (ws_size >= need) {
        qhp = (_Float16*)d_ws;
    } else {
        qhp = (_Float16*)ctx;   // 1.25 MB fits ctx's 2 MB; overwritten by context_k last
    }
    _Float16* wp2 = qhp + (size_t)B_ * S_ * E2_;

    prep_qhp<<<dim3(512), dim3(256), 0, stream>>>(query, qhp);
    prep_w<<<dim3(512), dim3(256), 0, stream>>>(Wd, wp2);
    // dense triangular grid: 10 tile-pairs * 128 s-values = 1280 blocks per batch
    stage1<<<dim3(1280, B_), dim3(512), 0, stream>>>(qhp, wp2, qhp, vd, atten);
    softmax_k<<<dim3(B_ * S_), dim3(64), 0, stream>>>(atten);
    context_k<<<dim3(E2_ / 64, S_ / 32, B_), dim3(256), 0, stream>>>(atten, value, ctx);
}

// Round 16
// 157.749 us; speedup vs baseline: 1.3572x; 1.3572x over previous
//
#include <hip/hip_runtime.h>

#define B_  2
#define S_  512
#define E2_ 512
#define E_  256

#define TT  128   // t-tile per block (stage1)
#define KB  32    // k-tile per step
#define LDK 40    // padded LDS row stride for sA (80 B, 16B-aligned, bank-clean)

using f32x4 = __attribute__((ext_vector_type(4))) float;
using f16x8 = __attribute__((ext_vector_type(8))) _Float16;

__device__ __forceinline__ float tanh_fast(float x) {
    // NaN-safe: e->inf gives 1-0=1 ; e->0 gives 1-2=-1
    float e = __expf(2.0f * x);
    return 1.0f - 2.0f / (e + 1.0f);
}

#define SBAR() __builtin_amdgcn_sched_barrier(0)

// ---- prep: qh f16 copy of q (524288 elems) + Wp2 step-tiled f16 W (131072) -----
__global__ void prep_all(const float* __restrict__ q, _Float16* __restrict__ qh,
                         const float* __restrict__ Wd, _Float16* __restrict__ Wp2) {
    int idx = blockIdx.x * 256 + threadIdx.x;   // 0 .. 131071
    // q -> qh, 4 elems/thread
    float4 v = *(const float4*)(q + idx * 4);
    _Float16 h4[4] = {(_Float16)v.x, (_Float16)v.y, (_Float16)v.z, (_Float16)v.w};
    *(short4*)(qh + idx * 4) = *(short4*)h4;
    // Wd[h][d] -> Wp2[ko][d][kk], 1 elem/thread
    int h = idx >> 8;      // k index 0..511
    int d = idx & 255;     // 0..255
    int ko = h >> 5;
    int kk = h & 31;
    Wp2[ko * (E_ * KB) + d * KB + kk] = (_Float16)Wd[idx];
}

// ---------------- stage1: logits[b,s,t], dense triangular grid -------------------
// blockIdx.x in [0,1280): p = x>>7 tile-pair (ti<=sj), sl = x&127 selects s
__global__ __launch_bounds__(512, 4)
void stage1(const _Float16* __restrict__ qh,
            const _Float16* __restrict__ Wp2,
            const float* __restrict__ vd,
            float* __restrict__ logits /* [B*S, S] */) {
    const int p  = blockIdx.x >> 7;
    const int sl = blockIdx.x & 127;
    const int b  = blockIdx.y;
    const int sj = (p >= 6) ? 3 : (p >= 3) ? 2 : (p >= 1) ? 1 : 0;
    const int ti = p - ((sj * (sj + 1)) >> 1);
    const int s  = sj * TT + sl;
    const int t0 = ti * TT;

    __shared__ _Float16 sA[2][TT * LDK];   // 2 x 10 KiB (pure qh_t copies)
    __shared__ _Float16 sQsh[E2_];         // 1 KiB (qh_s row)
    __shared__ float sVd[E_];              // 1 KiB

    const int tid = threadIdx.x;   // 0..511
    {
        sQsh[tid] = qh[((size_t)(b * S_ + s)) * E2_ + tid];
        if (tid < E_) sVd[tid] = vd[tid];
    }
    __syncthreads();

    const int wave = tid >> 6;    // 0..7
    const int lane = tid & 63;
    const int wt   = wave >> 2;   // 0..1 : t-half (64 rows)
    const int wd   = wave & 3;    // 0..3 : d-quarter (64 cols)
    const int l15  = lane & 15;
    const int l4   = lane >> 4;   // 0..3

    // A staging: thread -> row = tid>>2 (0..127), granule = tid&3 (8 f16 each)
    const int a_row = tid >> 2;
    const int a_g   = tid & 3;
    const int a_off = a_row * LDK + a_g * 8;
    const _Float16* qt = qh + ((size_t)(b * S_ + t0 + a_row)) * E2_ + a_g * 8;

    // B fragments: direct global->reg from compact Wp2 (L2-resident, coalesced)
    const _Float16* wpb = Wp2 + (wd * 64 + l15) * KB + l4 * 8;   // + fd*16*KB + ko*E_*KB

    f16x8 ra;                          // A prefetch register (pure copy)
    auto ALOAD  = [&](int k0) { ra = *(const f16x8*)(qt + k0); };
    auto AWRITE = [&](int h)  { *(f16x8*)&sA[h][a_off] = ra; };

    f32x4 acc[4][4] = {};
    f16x8 ring[6];                     // bf software-pipeline ring, depth 6 phases

    // ---- one fd-phase: consume ring[q%6], then reload that slot for phase q+6 ---
#define PHASE(KO, J)                                                          \
    {                                                                         \
        constexpr int q_ = (KO) * 4 + (J);                                    \
        __builtin_amdgcn_s_setprio(1);                                        \
        _Pragma("unroll")                                                     \
        for (int ft = 0; ft < 4; ++ft)                                        \
            acc[ft][(J)] = __builtin_amdgcn_mfma_f32_16x16x32_f16(            \
                af[ft], ring[q_ % 6], acc[ft][(J)], 0, 0, 0);                 \
        __builtin_amdgcn_s_setprio(0);                                        \
        if constexpr (q_ + 6 < 64) {                                          \
            constexpr int qq = q_ + 6;                                        \
            ring[q_ % 6] = *(const f16x8*)(wpb + (qq >> 2) * (E_ * KB)        \
                                               + (qq & 3) * 16 * KB);         \
        }                                                                     \
        SBAR();                                                               \
    }

    // ---- one K-step: A-path (r13-proven) + 4 ring phases -----------------------
#define STEP(KO)                                                              \
    {                                                                         \
        f16x8 af[4];                                                          \
        _Pragma("unroll")                                                     \
        for (int ft = 0; ft < 4; ++ft) {                                      \
            int row = wt * 64 + ft * 16 + l15;                                \
            af[ft] = *(const f16x8*)&sA[(KO) & 1][row * LDK + l4 * 8];        \
        }                                                                     \
        f16x8 qsv = *(const f16x8*)&sQsh[(KO) * KB + l4 * 8];                 \
        SBAR();                                                               \
        if ((KO) < 15) { AWRITE(((KO) & 1) ^ 1); SBAR(); }                    \
        if ((KO) < 14) { ALOAD(((KO) + 2) * KB); SBAR(); }                    \
        if ((KO) < 15) {                                                      \
            asm volatile("s_waitcnt lgkmcnt(0)" ::: "memory");                \
            __builtin_amdgcn_s_barrier();                                     \
            SBAR();                                                           \
        }                                                                     \
        _Pragma("unroll")                                                     \
        for (int ft = 0; ft < 4; ++ft) af[ft] = af[ft] * qsv;                 \
        PHASE(KO, 0) PHASE(KO, 1) PHASE(KO, 2) PHASE(KO, 3)                   \
    }

    // prologue — A pipeline (r13) + ring preload (6 slots = phases 0..5)
    ALOAD(0);
    SBAR();
    AWRITE(0);             // compiler inserts exact vmcnt wait for ra
    SBAR();
#pragma unroll
    for (int q = 0; q < 6; ++q)
        ring[q] = *(const f16x8*)(wpb + (q >> 2) * (E_ * KB) + (q & 3) * 16 * KB);
    SBAR();
    ALOAD(KB);             // stays in flight across the barrier
    SBAR();
    asm volatile("s_waitcnt lgkmcnt(0)" ::: "memory");
    __builtin_amdgcn_s_barrier();
    SBAR();

    STEP(0)  STEP(1)  STEP(2)  STEP(3)
    STEP(4)  STEP(5)  STEP(6)  STEP(7)
    STEP(8)  STEP(9)  STEP(10) STEP(11)
    STEP(12) STEP(13) STEP(14) STEP(15)

#undef STEP
#undef PHASE

    __syncthreads();   // all frag reads done -> sA reusable as sRed

    // ---- epilogue: tanh, *vd, reduce over d
    float* sRed = (float*)&sA[0][0];   // TT*4 floats
    {
        float vdr[4];
#pragma unroll
        for (int fd = 0; fd < 4; ++fd) vdr[fd] = sVd[wd * 64 + fd * 16 + l15];
#pragma unroll
        for (int ft = 0; ft < 4; ++ft) {
#pragma unroll
            for (int r = 0; r < 4; ++r) {
                float pp = 0.f;
#pragma unroll
                for (int fd = 0; fd < 4; ++fd)
                    pp += tanh_fast(acc[ft][fd][r]) * vdr[fd];
                pp += __shfl_xor(pp, 1);
                pp += __shfl_xor(pp, 2);
                pp += __shfl_xor(pp, 4);
                pp += __shfl_xor(pp, 8);
                if (l15 == 0) {
                    int tl = wt * 64 + ft * 16 + l4 * 4 + r;
                    sRed[tl * 4 + wd] = pp;
                }
            }
        }
    }
    __syncthreads();
    if (tid < TT) {
        float v = sRed[tid * 4 + 0] + sRed[tid * 4 + 1] + sRed[tid * 4 + 2] + sRed[tid * 4 + 3];
        int t = t0 + tid;
        logits[((size_t)(b * S_ + s)) * S_ + t] = v;   // direct
        logits[((size_t)(b * S_ + t)) * S_ + s] = v;   // mirror (bitwise-identical)
    }
}

// ---------------- softmax in place over rows of 512 ------------------------------
__global__ void softmax_k(float* __restrict__ atten) {
    const int row  = blockIdx.x;
    const int lane = threadIdx.x;
    float* p = atten + (size_t)row * S_;
    float4 v0 = *(float4*)(p + lane * 8);
    float4 v1 = *(float4*)(p + lane * 8 + 4);
    float vv[8] = {v0.x, v0.y, v0.z, v0.w, v1.x, v1.y, v1.z, v1.w};
    float m = vv[0];
#pragma unroll
    for (int j = 1; j < 8; ++j) m = fmaxf(m, vv[j]);
#pragma unroll
    for (int off = 1; off < 64; off <<= 1) m = fmaxf(m, __shfl_xor(m, off));
    float ssum = 0.f;
#pragma unroll
    for (int j = 0; j < 8; ++j) { vv[j] = __expf(vv[j] - m); ssum += vv[j]; }
#pragma unroll
    for (int off = 1; off < 64; off <<= 1) ssum += __shfl_xor(ssum, off);
    float inv = 1.0f / ssum;
    float4 o0 = {vv[0] * inv, vv[1] * inv, vv[2] * inv, vv[3] * inv};
    float4 o1 = {vv[4] * inv, vv[5] * inv, vv[6] * inv, vv[7] * inv};
    *(float4*)(p + lane * 8)     = o0;
    *(float4*)(p + lane * 8 + 4) = o1;
}

// ---------------- context = atten @ value (f32 tiled) -----------------------------
__global__ __launch_bounds__(256)
void context_k(const float* __restrict__ atten, const float* __restrict__ value,
               float* __restrict__ ctx) {
    __shared__ float sA[32][65];
    __shared__ float sV[64][65];
    const int b  = blockIdx.z;
    const int s0 = blockIdx.y * 32;
    const int e0 = blockIdx.x * 64;
    const int tid = threadIdx.x;
    const int ts = tid >> 4;
    const int te = tid & 15;

    float acc[2][4] = {};
    for (int k0 = 0; k0 < S_; k0 += 64) {
        {
            int r = tid >> 3;
            int c = (tid & 7) * 8;
            const float* ga = atten + ((size_t)(b * S_ + s0 + r)) * S_ + k0 + c;
            *(float4*)&sA[r][c]     = *(const float4*)ga;
            *(float4*)&sA[r][c + 4] = *(const float4*)(ga + 4);
        }
        {
            int r = tid >> 2;
            int c = (tid & 3) * 16;
            const float* gv = value + ((size_t)(b * S_ + k0 + r)) * E2_ + e0 + c;
#pragma unroll
            for (int j = 0; j < 16; j += 4)
                *(float4*)&sV[r][c + j] = *(const float4*)(gv + j);
        }
        __syncthreads();
#pragma unroll 8
        for (int kk = 0; kk < 64; ++kk) {
            float a0 = sA[ts * 2 + 0][kk];
            float a1 = sA[ts * 2 + 1][kk];
#pragma unroll
            for (int j = 0; j < 4; ++j) {
                float vvv = sV[kk][te * 4 + j];
                acc[0][j] += a0 * vvv;
                acc[1][j] += a1 * vvv;
            }
        }
        __syncthreads();
    }
#pragma unroll
    for (int i = 0; i < 2; ++i)
#pragma unroll
        for (int j = 0; j < 4; ++j)
            ctx[((size_t)(b * S_ + s0 + ts * 2 + i)) * E2_ + e0 + te * 4 + j] = acc[i][j];
}

extern "C" void kernel_launch(void* const* d_in, const int* in_sizes, int n_in,
                              void* d_out, int out_size, void* d_ws, size_t ws_size,
                              hipStream_t stream) {
    const float* query = (const float*)d_in[0];
    const float* value = (const float*)d_in[1];
    const float* Wd    = (const float*)d_in[2];
    const float* vd    = (const float*)d_in[3];

    float* out   = (float*)d_out;
    float* ctx   = out;                          // [B,S,E2]  (2 MB)
    float* atten = out + (size_t)B_ * S_ * E2_;  // [B,S,S]

    // scratch: qh (1 MB) + Wp2 (256 KB)
    const size_t need = (size_t)(B_ * S_ * E2_ + 16 * E_ * KB) * sizeof(_Float16);
    _Float16* qh;
    if (ws_size >= need) {
        qh = (_Float16*)d_ws;
    } else {
        qh = (_Float16*)ctx;   // 1.25 MB fits in ctx's 2 MB; overwritten by context_k last
    }
    _Float16* wp2 = qh + (size_t)B_ * S_ * E2_;

    prep_all<<<dim3(512), dim3(256), 0, stream>>>(query, qh, Wd, wp2);
    // dense triangular grid: 10 tile-pairs * 128 s-values = 1280 blocks per batch
    stage1<<<dim3(1280, B_), dim3(512), 0, stream>>>(qh, wp2, vd, atten);
    softmax_k<<<dim3(B_ * S_), dim3(64), 0, stream>>>(atten);
    context_k<<<dim3(E2_ / 64, S_ / 32, B_), dim3(256), 0, stream>>>(atten, value, ctx);
}

// Round 17
// 144.990 us; speedup vs baseline: 1.4767x; 1.0880x over previous
//
#include <hip/hip_runtime.h>

#define B_  2
#define S_  512
#define E2_ 512
#define E_  256

#define TT  64    // t-tile per block (stage1)
#define KB  32    // k-tile per step
#define LDK 40    // padded LDS row stride for sA (80 B, 16B-aligned, bank-clean)

using f32x4 = __attribute__((ext_vector_type(4))) float;
using f16x8 = __attribute__((ext_vector_type(8))) _Float16;

__device__ __forceinline__ float tanh_fast(float x) {
    // NaN-safe: e->inf gives 1-0=1 ; e->0 gives 1-2=-1
    float e = __expf(2.0f * x);
    return 1.0f - 2.0f / (e + 1.0f);
}

#define SBAR() __builtin_amdgcn_sched_barrier(0)

// ---- prep: qh f16 copy of q (524288 elems) + Wp2 step-tiled f16 W (131072) -----
__global__ void prep_all(const float* __restrict__ q, _Float16* __restrict__ qh,
                         const float* __restrict__ Wd, _Float16* __restrict__ Wp2) {
    int idx = blockIdx.x * 256 + threadIdx.x;   // 0 .. 131071
    // q -> qh, 4 elems/thread
    float4 v = *(const float4*)(q + idx * 4);
    _Float16 h4[4] = {(_Float16)v.x, (_Float16)v.y, (_Float16)v.z, (_Float16)v.w};
    *(short4*)(qh + idx * 4) = *(short4*)h4;
    // Wd[h][d] -> Wp2[ko][d][kk], 1 elem/thread
    int h = idx >> 8;      // k index 0..511
    int d = idx & 255;     // 0..255
    int ko = h >> 5;
    int kk = h & 31;
    Wp2[ko * (E_ * KB) + d * KB + kk] = (_Float16)Wd[idx];
}

// ---------------- stage1: logits[b,s,t], dense triangular grid -------------------
// 8 t-tiles of 64; 36 unordered tile-pairs (ti<=sj); blockIdx.x = p*64 + sl.
// 4 waves/block (one 64x64 output quarter each along d) -> per-SIMD phase diversity.
__global__ __launch_bounds__(256, 4)
void stage1(const _Float16* __restrict__ qh,
            const _Float16* __restrict__ Wp2,
            const float* __restrict__ vd,
            float* __restrict__ logits /* [B*S, S] */) {
    const int x  = blockIdx.x;
    const int p  = x >> 6;          // 0..35
    const int sl = x & 63;
    const int b  = blockIdx.y;
    int sj = 0;
    while ((sj + 1) * (sj + 2) / 2 <= p) ++sj;   // triangular decode, <=8 iters
    const int ti = p - sj * (sj + 1) / 2;
    const int s  = sj * TT + sl;
    const int t0 = ti * TT;

    __shared__ _Float16 sA[2][TT * LDK];   // 2 x 5 KiB (pure qh_t copies)
    __shared__ _Float16 sQsh[E2_];         // 1 KiB (qh_s row)
    __shared__ float sVd[E_];              // 1 KiB

    const int tid = threadIdx.x;   // 0..255
    {
        const _Float16* qsrow = qh + ((size_t)(b * S_ + s)) * E2_;
        sQsh[tid]       = qsrow[tid];
        sQsh[tid + 256] = qsrow[tid + 256];
        sVd[tid & 255]  = vd[tid & 255];
    }
    __syncthreads();

    const int wave = tid >> 6;    // 0..3
    const int lane = tid & 63;
    const int wd   = wave;        // d-quarter (64 cols)
    const int l15  = lane & 15;
    const int l4   = lane >> 4;   // 0..3

    // A staging: thread -> row = tid>>2 (0..63), granule = tid&3 (8 f16 each)
    const int a_row = tid >> 2;
    const int a_g   = tid & 3;
    const int a_off = a_row * LDK + a_g * 8;
    const _Float16* qt = qh + ((size_t)(b * S_ + t0 + a_row)) * E2_ + a_g * 8;

    // B fragments: direct global->reg from compact Wp2 (L2-resident, coalesced 1KB/wave)
    const _Float16* wpb = Wp2 + (wd * 64 + l15) * KB + l4 * 8;   // + fd*16*KB + ko*E_*KB

    f16x8 ra;                          // A prefetch register (pure copy)
    auto ALOAD  = [&](int k0) { ra = *(const f16x8*)(qt + k0); };
    auto AWRITE = [&](int h)  { *(f16x8*)&sA[h][a_off] = ra; };

    f32x4 acc[4][4] = {};

    // prologue
    ALOAD(0);
    SBAR();
    AWRITE(0);             // compiler inserts exact vmcnt wait for ra
    SBAR();
    ALOAD(KB);             // stays in flight across the barrier
    SBAR();
    asm volatile("s_waitcnt lgkmcnt(0)" ::: "memory");
    __builtin_amdgcn_s_barrier();
    SBAR();

    for (int ko = 0; ko < E2_ / KB; ++ko) {
        const int h = ko & 1;
        const int k0 = ko * KB;
        // B frags for THIS step: 4 coalesced global b128 loads (reg-dest)
        f16x8 bf[4];
        {
            const _Float16* wk = wpb + ko * (E_ * KB);
#pragma unroll
            for (int fd = 0; fd < 4; ++fd)
                bf[fd] = *(const f16x8*)(wk + fd * 16 * KB);
        }
        SBAR();
        // A frags (pure qt rows) + qs slice from LDS
        f16x8 af[4];
#pragma unroll
        for (int ft = 0; ft < 4; ++ft) {
            int row = ft * 16 + l15;
            af[ft] = *(const f16x8*)&sA[h][row * LDK + l4 * 8];
        }
        f16x8 qsv = *(const f16x8*)&sQsh[k0 + l4 * 8];
        SBAR();
        if (ko < 15) { AWRITE(h ^ 1); SBAR(); }          // uses ra from prev ALOAD
        if (ko < 14) { ALOAD((ko + 2) * KB); SBAR(); }   // reg-dest, spans barrier
        if (ko < 15) {
            asm volatile("s_waitcnt lgkmcnt(0)" ::: "memory");  // LDS ops only
            __builtin_amdgcn_s_barrier();
            SBAR();
        }
        // fold qs into A-fragment in-register (proven numerics)
        f16x8 pa[4];
#pragma unroll
        for (int ft = 0; ft < 4; ++ft) pa[ft] = af[ft] * qsv;   // v_pk_mul_f16 x4
        __builtin_amdgcn_s_setprio(1);
#pragma unroll
        for (int ft = 0; ft < 4; ++ft)
#pragma unroll
            for (int fd = 0; fd < 4; ++fd)
                acc[ft][fd] = __builtin_amdgcn_mfma_f32_16x16x32_f16(pa[ft], bf[fd], acc[ft][fd], 0, 0, 0);
        __builtin_amdgcn_s_setprio(0);
    }

    __syncthreads();   // all frag reads done -> sA reusable as sRed

    // ---- epilogue: tanh, *vd, reduce over d
    float* sRed = (float*)&sA[0][0];   // TT*4 floats
    {
        float vdr[4];
#pragma unroll
        for (int fd = 0; fd < 4; ++fd) vdr[fd] = sVd[wd * 64 + fd * 16 + l15];
#pragma unroll
        for (int ft = 0; ft < 4; ++ft) {
#pragma unroll
            for (int r = 0; r < 4; ++r) {
                float pp = 0.f;
#pragma unroll
                for (int fd = 0; fd < 4; ++fd)
                    pp += tanh_fast(acc[ft][fd][r]) * vdr[fd];
                pp += __shfl_xor(pp, 1);
                pp += __shfl_xor(pp, 2);
                pp += __shfl_xor(pp, 4);
                pp += __shfl_xor(pp, 8);
                if (l15 == 0) {
                    int tl = ft * 16 + l4 * 4 + r;
                    sRed[tl * 4 + wd] = pp;
                }
            }
        }
    }
    __syncthreads();
    if (tid < TT) {
        float v = sRed[tid * 4 + 0] + sRed[tid * 4 + 1] + sRed[tid * 4 + 2] + sRed[tid * 4 + 3];
        int t = t0 + tid;
        logits[((size_t)(b * S_ + s)) * S_ + t] = v;   // direct
        logits[((size_t)(b * S_ + t)) * S_ + s] = v;   // mirror (bitwise-identical)
    }
}

// ---------------- softmax in place over rows of 512 ------------------------------
__global__ void softmax_k(float* __restrict__ atten) {
    const int row  = blockIdx.x;
    const int lane = threadIdx.x;
    float* p = atten + (size_t)row * S_;
    float4 v0 = *(float4*)(p + lane * 8);
    float4 v1 = *(float4*)(p + lane * 8 + 4);
    float vv[8] = {v0.x, v0.y, v0.z, v0.w, v1.x, v1.y, v1.z, v1.w};
    float m = vv[0];
#pragma unroll
    for (int j = 1; j < 8; ++j) m = fmaxf(m, vv[j]);
#pragma unroll
    for (int off = 1; off < 64; off <<= 1) m = fmaxf(m, __shfl_xor(m, off));
    float ssum = 0.f;
#pragma unroll
    for (int j = 0; j < 8; ++j) { vv[j] = __expf(vv[j] - m); ssum += vv[j]; }
#pragma unroll
    for (int off = 1; off < 64; off <<= 1) ssum += __shfl_xor(ssum, off);
    float inv = 1.0f / ssum;
    float4 o0 = {vv[0] * inv, vv[1] * inv, vv[2] * inv, vv[3] * inv};
    float4 o1 = {vv[4] * inv, vv[5] * inv, vv[6] * inv, vv[7] * inv};
    *(float4*)(p + lane * 8)     = o0;
    *(float4*)(p + lane * 8 + 4) = o1;
}

// ---------------- context = atten @ value (f32 tiled) -----------------------------
__global__ __launch_bounds__(256)
void context_k(const float* __restrict__ atten, const float* __restrict__ value,
               float* __restrict__ ctx) {
    __shared__ float sA[32][65];
    __shared__ float sV[64][65];
    const int b  = blockIdx.z;
    const int s0 = blockIdx.y * 32;
    const int e0 = blockIdx.x * 64;
    const int tid = threadIdx.x;
    const int ts = tid >> 4;
    const int te = tid & 15;

    float acc[2][4] = {};
    for (int k0 = 0; k0 < S_; k0 += 64) {
        {
            int r = tid >> 3;
            int c = (tid & 7) * 8;
            const float* ga = atten + ((size_t)(b * S_ + s0 + r)) * S_ + k0 + c;
            *(float4*)&sA[r][c]     = *(const float4*)ga;
            *(float4*)&sA[r][c + 4] = *(const float4*)(ga + 4);
        }
        {
            int r = tid >> 2;
            int c = (tid & 3) * 16;
            const float* gv = value + ((size_t)(b * S_ + k0 + r)) * E2_ + e0 + c;
#pragma unroll
            for (int j = 0; j < 16; j += 4)
                *(float4*)&sV[r][c + j] = *(const float4*)(gv + j);
        }
        __syncthreads();
#pragma unroll 8
        for (int kk = 0; kk < 64; ++kk) {
            float a0 = sA[ts * 2 + 0][kk];
            float a1 = sA[ts * 2 + 1][kk];
#pragma unroll
            for (int j = 0; j < 4; ++j) {
                float vvv = sV[kk][te * 4 + j];
                acc[0][j] += a0 * vvv;
                acc[1][j] += a1 * vvv;
            }
        }
        __syncthreads();
    }
#pragma unroll
    for (int i = 0; i < 2; ++i)
#pragma unroll
        for (int j = 0; j < 4; ++j)
            ctx[((size_t)(b * S_ + s0 + ts * 2 + i)) * E2_ + e0 + te * 4 + j] = acc[i][j];
}

extern "C" void kernel_launch(void* const* d_in, const int* in_sizes, int n_in,
                              void* d_out, int out_size, void* d_ws, size_t ws_size,
                              hipStream_t stream) {
    const float* query = (const float*)d_in[0];
    const float* value = (const float*)d_in[1];
    const float* Wd    = (const float*)d_in[2];
    const float* vd    = (const float*)d_in[3];

    float* out   = (float*)d_out;
    float* ctx   = out;                          // [B,S,E2]  (2 MB)
    float* atten = out + (size_t)B_ * S_ * E2_;  // [B,S,S]

    // scratch: qh (1 MB) + Wp2 (256 KB)
    const size_t need = (size_t)(B_ * S_ * E2_ + 16 * E_ * KB) * sizeof(_Float16);
    _Float16* qh;
    if (ws_size >= need) {
        qh = (_Float16*)d_ws;
    } else {
        qh = (_Float16*)ctx;   // 1.25 MB fits in ctx's 2 MB; overwritten by context_k last
    }
    _Float16* wp2 = qh + (size_t)B_ * S_ * E2_;

    prep_all<<<dim3(512), dim3(256), 0, stream>>>(query, qh, Wd, wp2);
    // dense triangular grid: 36 tile-pairs * 64 s-values = 2304 blocks per batch
    stage1<<<dim3(2304, B_), dim3(256), 0, stream>>>(qh, wp2, vd, atten);
    softmax_k<<<dim3(B_ * S_), dim3(64), 0, stream>>>(atten);
    context_k<<<dim3(E2_ / 64, S_ / 32, B_), dim3(256), 0, stream>>>(atten, value, ctx);
}

// Round 18
// 143.354 us; speedup vs baseline: 1.4935x; 1.0114x over previous
//
#include <hip/hip_runtime.h>

#define B_  2
#define S_  512
#define E2_ 512
#define E_  256

#define TT  64    // t-tile per block (stage1)
#define KB  32    // Wp2 slice granularity (layout unchanged)
#define KS  64    // k per step (2 slices)
#define LDK 72    // padded LDS row stride for sA (144 B, 16B-aligned, 2-way-clean)

using f32x4 = __attribute__((ext_vector_type(4))) float;
using f16x8 = __attribute__((ext_vector_type(8))) _Float16;

__device__ __forceinline__ float tanh_fast(float x) {
    // NaN-safe: e->inf gives 1-0=1 ; e->0 gives 1-2=-1
    float e = __expf(2.0f * x);
    return 1.0f - 2.0f / (e + 1.0f);
}

#define SBAR() __builtin_amdgcn_sched_barrier(0)

// ---- prep: qh f16 copy of q (524288 elems) + Wp2 step-tiled f16 W (131072) -----
__global__ void prep_all(const float* __restrict__ q, _Float16* __restrict__ qh,
                         const float* __restrict__ Wd, _Float16* __restrict__ Wp2) {
    int idx = blockIdx.x * 256 + threadIdx.x;   // 0 .. 131071
    // q -> qh, 4 elems/thread
    float4 v = *(const float4*)(q + idx * 4);
    _Float16 h4[4] = {(_Float16)v.x, (_Float16)v.y, (_Float16)v.z, (_Float16)v.w};
    *(short4*)(qh + idx * 4) = *(short4*)h4;
    // Wd[h][d] -> Wp2[ko][d][kk], 1 elem/thread
    int h = idx >> 8;      // k index 0..511
    int d = idx & 255;     // 0..255
    int ko = h >> 5;
    int kk = h & 31;
    Wp2[ko * (E_ * KB) + d * KB + kk] = (_Float16)Wd[idx];
}

// ---------------- stage1: logits[b,s,t], dense triangular grid -------------------
// 8 t-tiles of 64; 36 unordered tile-pairs (ti<=sj); blockIdx.x = p*64 + sl.
// 4 waves/block; K-loop = 8 steps of 64 (one barrier per 32 MFMA).
__global__ __launch_bounds__(256, 4)
void stage1(const _Float16* __restrict__ qh,
            const _Float16* __restrict__ Wp2,
            const float* __restrict__ vd,
            float* __restrict__ logits /* [B*S, S] */) {
    const int x  = blockIdx.x;
    const int p  = x >> 6;          // 0..35
    const int sl = x & 63;
    const int b  = blockIdx.y;
    int sj = 0;
    while ((sj + 1) * (sj + 2) / 2 <= p) ++sj;   // triangular decode
    const int ti = p - sj * (sj + 1) / 2;
    const int s  = sj * TT + sl;
    const int t0 = ti * TT;

    __shared__ _Float16 sA[2][TT * LDK];   // 2 x 9 KiB (pure qh_t copies)
    __shared__ _Float16 sQsh[E2_];         // 1 KiB (qh_s row)
    __shared__ float sVd[E_];              // 1 KiB

    const int tid = threadIdx.x;   // 0..255
    {
        const _Float16* qsrow = qh + ((size_t)(b * S_ + s)) * E2_;
        sQsh[tid]       = qsrow[tid];
        sQsh[tid + 256] = qsrow[tid + 256];
        sVd[tid & 255]  = vd[tid & 255];
    }
    __syncthreads();

    const int wave = tid >> 6;    // 0..3
    const int lane = tid & 63;
    const int wd   = wave;        // d-quarter (64 cols)
    const int l15  = lane & 15;
    const int l4   = lane >> 4;   // 0..3

    // A staging: thread -> row = tid>>2 (0..63), 16 f16 at k-offset (tid&3)*16
    const int a_row = tid >> 2;
    const int a_g   = tid & 3;
    const int a_off = a_row * LDK + a_g * 16;
    const _Float16* qt = qh + ((size_t)(b * S_ + t0 + a_row)) * E2_ + a_g * 16;

    // B fragments: direct global->reg from compact Wp2 (L2-resident, coalesced 1KB/wave)
    const _Float16* wpb = Wp2 + (wd * 64 + l15) * KB + l4 * 8;   // + fd*16*KB + slice*E_*KB

    f16x8 ra0, ra1;                    // A prefetch registers (pure copy, 16 f16)
    auto ALOAD = [&](int j) {          // stage tile for step j
        ra0 = *(const f16x8*)(qt + j * KS);
        ra1 = *(const f16x8*)(qt + j * KS + 8);
    };
    auto AWRITE = [&](int hh) {
        *(f16x8*)&sA[hh][a_off]     = ra0;
        *(f16x8*)&sA[hh][a_off + 8] = ra1;
    };

    f32x4 acc[4][4] = {};

    // prologue
    ALOAD(0);
    SBAR();
    AWRITE(0);             // compiler inserts exact vmcnt wait for ra
    SBAR();
    ALOAD(1);              // stays in flight across the barrier
    SBAR();
    asm volatile("s_waitcnt lgkmcnt(0)" ::: "memory");
    __builtin_amdgcn_s_barrier();
    SBAR();

    for (int ko = 0; ko < 8; ++ko) {
        const int h  = ko & 1;
        const int k0 = ko * KS;
        f16x8 bf[4], af[4], qsv, pa[4];

        // ---- k-half 0 ----
        {
            const _Float16* wk = wpb + (2 * ko) * (E_ * KB);
#pragma unroll
            for (int fd = 0; fd < 4; ++fd)
                bf[fd] = *(const f16x8*)(wk + fd * 16 * KB);
        }
#pragma unroll
        for (int ft = 0; ft < 4; ++ft) {
            int row = ft * 16 + l15;
            af[ft] = *(const f16x8*)&sA[h][row * LDK + l4 * 8];
        }
        qsv = *(const f16x8*)&sQsh[k0 + l4 * 8];
        SBAR();
#pragma unroll
        for (int ft = 0; ft < 4; ++ft) pa[ft] = af[ft] * qsv;
        __builtin_amdgcn_s_setprio(1);
#pragma unroll
        for (int ft = 0; ft < 4; ++ft)
#pragma unroll
            for (int fd = 0; fd < 4; ++fd)
                acc[ft][fd] = __builtin_amdgcn_mfma_f32_16x16x32_f16(pa[ft], bf[fd], acc[ft][fd], 0, 0, 0);
        __builtin_amdgcn_s_setprio(0);
        SBAR();

        // ---- k-half 1 (loads overlap MFMA half 0 via scheduler) ----
        {
            const _Float16* wk = wpb + (2 * ko + 1) * (E_ * KB);
#pragma unroll
            for (int fd = 0; fd < 4; ++fd)
                bf[fd] = *(const f16x8*)(wk + fd * 16 * KB);
        }
#pragma unroll
        for (int ft = 0; ft < 4; ++ft) {
            int row = ft * 16 + l15;
            af[ft] = *(const f16x8*)&sA[h][row * LDK + 32 + l4 * 8];
        }
        qsv = *(const f16x8*)&sQsh[k0 + 32 + l4 * 8];
        SBAR();
        if (ko < 7) { AWRITE(h ^ 1); SBAR(); }   // uses ra from prev ALOAD
        if (ko < 6) { ALOAD(ko + 2); SBAR(); }   // reg-dest, spans barrier
#pragma unroll
        for (int ft = 0; ft < 4; ++ft) pa[ft] = af[ft] * qsv;
        __builtin_amdgcn_s_setprio(1);
#pragma unroll
        for (int ft = 0; ft < 4; ++ft)
#pragma unroll
            for (int fd = 0; fd < 4; ++fd)
                acc[ft][fd] = __builtin_amdgcn_mfma_f32_16x16x32_f16(pa[ft], bf[fd], acc[ft][fd], 0, 0, 0);
        __builtin_amdgcn_s_setprio(0);
        SBAR();
        if (ko < 7) {
            asm volatile("s_waitcnt lgkmcnt(0)" ::: "memory");  // ds ops drained under MFMA
            __builtin_amdgcn_s_barrier();
            SBAR();
        }
    }

    __syncthreads();   // all frag reads done -> sA reusable as sRed

    // ---- epilogue: tanh, *vd, reduce over d
    float* sRed = (float*)&sA[0][0];   // TT*4 floats
    {
        float vdr[4];
#pragma unroll
        for (int fd = 0; fd < 4; ++fd) vdr[fd] = sVd[wd * 64 + fd * 16 + l15];
#pragma unroll
        for (int ft = 0; ft < 4; ++ft) {
#pragma unroll
            for (int r = 0; r < 4; ++r) {
                float pp = 0.f;
#pragma unroll
                for (int fd = 0; fd < 4; ++fd)
                    pp += tanh_fast(acc[ft][fd][r]) * vdr[fd];
                pp += __shfl_xor(pp, 1);
                pp += __shfl_xor(pp, 2);
                pp += __shfl_xor(pp, 4);
                pp += __shfl_xor(pp, 8);
                if (l15 == 0) {
                    int tl = ft * 16 + l4 * 4 + r;
                    sRed[tl * 4 + wd] = pp;
                }
            }
        }
    }
    __syncthreads();
    if (tid < TT) {
        float v = sRed[tid * 4 + 0] + sRed[tid * 4 + 1] + sRed[tid * 4 + 2] + sRed[tid * 4 + 3];
        int t = t0 + tid;
        logits[((size_t)(b * S_ + s)) * S_ + t] = v;   // direct
        logits[((size_t)(b * S_ + t)) * S_ + s] = v;   // mirror (bitwise-identical)
    }
}

// ---------------- softmax in place over rows of 512 ------------------------------
__global__ void softmax_k(float* __restrict__ atten) {
    const int row  = blockIdx.x;
    const int lane = threadIdx.x;
    float* p = atten + (size_t)row * S_;
    float4 v0 = *(float4*)(p + lane * 8);
    float4 v1 = *(float4*)(p + lane * 8 + 4);
    float vv[8] = {v0.x, v0.y, v0.z, v0.w, v1.x, v1.y, v1.z, v1.w};
    float m = vv[0];
#pragma unroll
    for (int j = 1; j < 8; ++j) m = fmaxf(m, vv[j]);
#pragma unroll
    for (int off = 1; off < 64; off <<= 1) m = fmaxf(m, __shfl_xor(m, off));
    float ssum = 0.f;
#pragma unroll
    for (int j = 0; j < 8; ++j) { vv[j] = __expf(vv[j] - m); ssum += vv[j]; }
#pragma unroll
    for (int off = 1; off < 64; off <<= 1) ssum += __shfl_xor(ssum, off);
    float inv = 1.0f / ssum;
    float4 o0 = {vv[0] * inv, vv[1] * inv, vv[2] * inv, vv[3] * inv};
    float4 o1 = {vv[4] * inv, vv[5] * inv, vv[6] * inv, vv[7] * inv};
    *(float4*)(p + lane * 8)     = o0;
    *(float4*)(p + lane * 8 + 4) = o1;
}

// ---------------- context = atten @ value (f32 tiled) -----------------------------
__global__ __launch_bounds__(256)
void context_k(const float* __restrict__ atten, const float* __restrict__ value,
               float* __restrict__ ctx) {
    __shared__ float sA[32][65];
    __shared__ float sV[64][65];
    const int b  = blockIdx.z;
    const int s0 = blockIdx.y * 32;
    const int e0 = blockIdx.x * 64;
    const int tid = threadIdx.x;
    const int ts = tid >> 4;
    const int te = tid & 15;

    float acc[2][4] = {};
    for (int k0 = 0; k0 < S_; k0 += 64) {
        {
            int r = tid >> 3;
            int c = (tid & 7) * 8;
            const float* ga = atten + ((size_t)(b * S_ + s0 + r)) * S_ + k0 + c;
            *(float4*)&sA[r][c]     = *(const float4*)ga;
            *(float4*)&sA[r][c + 4] = *(const float4*)(ga + 4);
        }
        {
            int r = tid >> 2;
            int c = (tid & 3) * 16;
            const float* gv = value + ((size_t)(b * S_ + k0 + r)) * E2_ + e0 + c;
#pragma unroll
            for (int j = 0; j < 16; j += 4)
                *(float4*)&sV[r][c + j] = *(const float4*)(gv + j);
        }
        __syncthreads();
#pragma unroll 8
        for (int kk = 0; kk < 64; ++kk) {
            float a0 = sA[ts * 2 + 0][kk];
            float a1 = sA[ts * 2 + 1][kk];
#pragma unroll
            for (int j = 0; j < 4; ++j) {
                float vvv = sV[kk][te * 4 + j];
                acc[0][j] += a0 * vvv;
                acc[1][j] += a1 * vvv;
            }
        }
        __syncthreads();
    }
#pragma unroll
    for (int i = 0; i < 2; ++i)
#pragma unroll
        for (int j = 0; j < 4; ++j)
            ctx[((size_t)(b * S_ + s0 + ts * 2 + i)) * E2_ + e0 + te * 4 + j] = acc[i][j];
}

extern "C" void kernel_launch(void* const* d_in, const int* in_sizes, int n_in,
                              void* d_out, int out_size, void* d_ws, size_t ws_size,
                              hipStream_t stream) {
    const float* query = (const float*)d_in[0];
    const float* value = (const float*)d_in[1];
    const float* Wd    = (const float*)d_in[2];
    const float* vd    = (const float*)d_in[3];

    float* out   = (float*)d_out;
    float* ctx   = out;                          // [B,S,E2]  (2 MB)
    float* atten = out + (size_t)B_ * S_ * E2_;  // [B,S,S]

    // scratch: qh (1 MB) + Wp2 (256 KB)
    const size_t need = (size_t)(B_ * S_ * E2_ + 16 * E_ * KB) * sizeof(_Float16);
    _Float16* qh;
    if (ws_size >= need) {
        qh = (_Float16*)d_ws;
    } else {
        qh = (_Float16*)ctx;   // 1.25 MB fits in ctx's 2 MB; overwritten by context_k last
    }
    _Float16* wp2 = qh + (size_t)B_ * S_ * E2_;

    prep_all<<<dim3(512), dim3(256), 0, stream>>>(query, qh, Wd, wp2);
    // dense triangular grid: 36 tile-pairs * 64 s-values = 2304 blocks per batch
    stage1<<<dim3(2304, B_), dim3(256), 0, stream>>>(qh, wp2, vd, atten);
    softmax_k<<<dim3(B_ * S_), dim3(64), 0, stream>>>(atten);
    context_k<<<dim3(E2_ / 64, S_ / 32, B_), dim3(256), 0, stream>>>(atten, value, ctx);
}